// Round 6
// baseline (85.567 us; speedup 1.0000x reference)
//
#include <hip/hip_runtime.h>

#define S_ 2048
#define D_ 64

typedef __bf16 bf16x4 __attribute__((ext_vector_type(4)));
typedef __bf16 bf16x8 __attribute__((ext_vector_type(8)));
typedef float f32x4 __attribute__((ext_vector_type(4)));
typedef float f32x16 __attribute__((ext_vector_type(16)));

__global__ __launch_bounds__(128, 2)
void fa_fwd(const float* __restrict__ qg, const float* __restrict__ kg,
            const float* __restrict__ vg, float* __restrict__ og) {
    __shared__ __attribute__((aligned(16))) __bf16 K_lds[2][64 * 64];   // [key][d]
    __shared__ __attribute__((aligned(16))) __bf16 V_lds[2][64 * 64];   // [d][key]
    __shared__ __attribute__((aligned(16))) __bf16 P_lds[2][32 * 64];   // per-wave [q][key]

    const int tid  = threadIdx.x;
    const int lane = tid & 63;
    const int wv   = tid >> 6;    // wave 0..1
    const int cq   = lane & 31;   // q-column this lane owns in all fragments
    const int h    = lane >> 5;   // half-wave index

    const int bid = blockIdx.x;          // 0..1023
    const int qb  = 31 - (bid >> 5);     // heavy q-tiles first
    const int bh  = bid & 31;
    const int q0w = qb * 64 + wv * 32;   // this wave's 32 q-rows

    const size_t base = (size_t)bh * (S_ * D_);
    const float* Q = qg + base;
    const float* K = kg + base;
    const float* V = vg + base;
    float*       O = og + base;

    // ---- Q fragments (B-operand: lane holds Q[q0w+cq][c*16+8h+j]), scaled 1/8 ----
    bf16x8 qf[4];
    {
        const float* Qr = Q + (size_t)(q0w + cq) * D_;
        #pragma unroll
        for (int c = 0; c < 4; ++c) {
            const int d0 = c * 16 + h * 8;
            f32x4 a = *(const f32x4*)(Qr + d0);
            f32x4 b = *(const f32x4*)(Qr + d0 + 4);
            bf16x8 f;
            #pragma unroll
            for (int j = 0; j < 4; ++j) {
                f[j]     = (__bf16)(a[j] * 0.125f);
                f[4 + j] = (__bf16)(b[j] * 0.125f);
            }
            qf[c] = f;
        }
    }

    f32x16 acc0, acc1;  // O^T accumulators, d-blocks 0/1; lane's q = cq
    #pragma unroll
    for (int i = 0; i < 16; ++i) { acc0[i] = 0.f; acc1[i] = 0.f; }
    float m_r = -1e30f, l_r = 0.f;

    // staging maps (128 threads)
    const int kk   = tid >> 1;          // K row 0..63
    const int kd   = (tid & 1) * 32;    // K d-base (32 floats)
    const int vkey = (tid & 15) * 4;    // V key-base (4 rows)
    const int vdb  = (tid >> 4) * 8;    // V d-base (8 cols)
    const int nt = qb + 1;
    const unsigned swq = (unsigned)((cq & 7) << 4);

    // ---- prologue loads (tile 0) ----
    f32x4 rk[8], rv[8];
    {
        const float* Kp = K + (size_t)kk * D_ + kd;
        #pragma unroll
        for (int i = 0; i < 8; ++i) rk[i] = *(const f32x4*)(Kp + 4 * i);
        const float* Vp = V + (size_t)vkey * D_ + vdb;
        #pragma unroll
        for (int i = 0; i < 4; ++i) {
            rv[2 * i]     = *(const f32x4*)(Vp + (size_t)i * D_);
            rv[2 * i + 1] = *(const f32x4*)(Vp + (size_t)i * D_ + 4);
        }
    }

    for (int t = 0; t < nt; ++t) {
        const int buf = t & 1;
        // ---- convert + LDS write of staged tile t ----
        {
            const unsigned swzk = (unsigned)((kk & 7) << 4);
            #pragma unroll
            for (int n = 0; n < 4; ++n) {
                bf16x8 w;
                #pragma unroll
                for (int j = 0; j < 4; ++j) {
                    w[j]     = (__bf16)rk[2 * n][j];
                    w[4 + j] = (__bf16)rk[2 * n + 1][j];
                }
                *(bf16x8*)(&K_lds[buf][kk * 64 + ((((unsigned)(2 * (kd + 8 * n))) ^ swzk) >> 1)]) = w;
            }
            #pragma unroll
            for (int j = 0; j < 8; ++j) {
                const int d = vdb + j;
                bf16x4 wt;
                #pragma unroll
                for (int i = 0; i < 4; ++i) wt[i] = (__bf16)rv[2 * i + (j >> 2)][j & 3];
                *(bf16x4*)(&V_lds[buf][d * 64 + ((((unsigned)(2 * vkey)) ^ ((unsigned)((d & 7) << 4))) >> 1)]) = wt;
            }
        }
        __syncthreads();

        // ---- prefetch tile t+1 (flies under compute) ----
        if (t + 1 < nt) {
            const int kv1 = (t + 1) * 64;
            const float* Kp = K + (size_t)(kv1 + kk) * D_ + kd;
            #pragma unroll
            for (int i = 0; i < 8; ++i) rk[i] = *(const f32x4*)(Kp + 4 * i);
            const float* Vp = V + (size_t)(kv1 + vkey) * D_ + vdb;
            #pragma unroll
            for (int i = 0; i < 4; ++i) {
                rv[2 * i]     = *(const f32x4*)(Vp + (size_t)i * D_);
                rv[2 * i + 1] = *(const f32x4*)(Vp + (size_t)i * D_ + 4);
            }
        }

        // diag tile: wv=0's keys 32..63 fully masked -> skip that half entirely
        const bool diag  = (t == qb);
        const bool full1 = !(diag && wv == 0);

        // ---- QK^T, swapped: S^T[key][q], q = cq lane-local ----
        f32x16 s0, s1;
        #pragma unroll
        for (int i = 0; i < 16; ++i) { s0[i] = 0.f; s1[i] = 0.f; }
        __builtin_amdgcn_s_setprio(1);
        #pragma unroll
        for (int c = 0; c < 4; ++c) {
            const unsigned co = (unsigned)(c * 32 + h * 16);
            bf16x8 a0 = *(const bf16x8*)(&K_lds[buf][cq * 64 + ((co ^ swq) >> 1)]);
            s0 = __builtin_amdgcn_mfma_f32_32x32x16_bf16(a0, qf[c], s0, 0, 0, 0);
        }
        if (full1) {
            #pragma unroll
            for (int c = 0; c < 4; ++c) {
                const unsigned co = (unsigned)(c * 32 + h * 16);
                bf16x8 a1 = *(const bf16x8*)(&K_lds[buf][(32 + cq) * 64 + ((co ^ swq) >> 1)]);
                s1 = __builtin_amdgcn_mfma_f32_32x32x16_bf16(a1, qf[c], s1, 0, 0, 0);
            }
        }
        __builtin_amdgcn_s_setprio(0);

        // ---- causal mask (diag only; one half per wave needs it) ----
        // C/D map: in-tile key = (reg&3) + 8*(reg>>2) + 4h (+32 for s1), col q = cq
        if (diag) {
            #pragma unroll
            for (int reg = 0; reg < 16; ++reg) {
                const int idx = (reg & 3) + 8 * (reg >> 2) + 4 * h;
                if (idx > cq) {
                    if (wv) s1[reg] = -1e30f;
                    else    s0[reg] = -1e30f;
                }
            }
        }

        // ---- row max: in-lane tree + one half-exchange shuffle ----
        float t8[8];
        #pragma unroll
        for (int i = 0; i < 8; ++i) {
            float a = fmaxf(s0[i], s0[i + 8]);
            if (full1) a = fmaxf(a, fmaxf(s1[i], s1[i + 8]));
            t8[i] = a;
        }
        float mx = fmaxf(fmaxf(fmaxf(t8[0], t8[4]), fmaxf(t8[1], t8[5])),
                         fmaxf(fmaxf(t8[2], t8[6]), fmaxf(t8[3], t8[7])));
        mx = fmaxf(mx, __shfl_xor(mx, 32));

        // ---- T13: defer rescale when running max unchanged ----
        if (!__all(mx <= m_r)) {
            const float mnew = fmaxf(m_r, mx);
            const float corr = __expf(m_r - mnew);
            m_r = mnew;
            l_r *= corr;
            #pragma unroll
            for (int i = 0; i < 16; ++i) { acc0[i] *= corr; acc1[i] *= corr; }
        }

        float ps = 0.f;
        #pragma unroll
        for (int i = 0; i < 16; ++i) { s0[i] = __expf(s0[i] - m_r); ps += s0[i]; }
        if (full1) {
            #pragma unroll
            for (int i = 0; i < 16; ++i) { s1[i] = __expf(s1[i] - m_r); ps += s1[i]; }
        }
        l_r += ps;

        // ---- P -> bf16, park in wave-private LDS [q][key] (swizzled) ----
        {
            __bf16* Pw = &P_lds[wv][cq * 64];
            #pragma unroll
            for (int m = 0; m < 4; ++m) {
                bf16x4 wa;
                #pragma unroll
                for (int j = 0; j < 4; ++j) wa[j] = (__bf16)s0[4 * m + j];
                *(bf16x4*)(&Pw[((((unsigned)(16 * m + 8 * h)) ^ swq) >> 1)]) = wa;
            }
            if (full1) {
                #pragma unroll
                for (int m = 0; m < 4; ++m) {
                    bf16x4 wb;
                    #pragma unroll
                    for (int j = 0; j < 4; ++j) wb[j] = (__bf16)s1[4 * m + j];
                    *(bf16x4*)(&Pw[((((unsigned)(64 + 16 * m + 8 * h)) ^ swq) >> 1)]) = wb;
                }
            }
        }

        // ---- PV, swapped: O^T[d][q] += V^T · P^T ----
        __builtin_amdgcn_s_setprio(1);
        const __bf16* Pw = &P_lds[wv][cq * 64];
        const int nks = full1 ? 4 : 2;
        #pragma unroll 4
        for (int ks = 0; ks < nks; ++ks) {
            const unsigned co = (unsigned)(ks * 32 + h * 16);
            bf16x8 pb  = *(const bf16x8*)(&Pw[((co ^ swq) >> 1)]);
            bf16x8 va0 = *(const bf16x8*)(&V_lds[buf][cq * 64 + ((co ^ swq) >> 1)]);
            bf16x8 va1 = *(const bf16x8*)(&V_lds[buf][(32 + cq) * 64 + ((co ^ swq) >> 1)]);
            acc0 = __builtin_amdgcn_mfma_f32_32x32x16_bf16(va0, pb, acc0, 0, 0, 0);
            acc1 = __builtin_amdgcn_mfma_f32_32x32x16_bf16(va1, pb, acc1, 0, 0, 0);
        }
        __builtin_amdgcn_s_setprio(0);
    }

    // ---- epilogue: combine l halves, normalize, store 16B chunks ----
    const float lsum = l_r + __shfl_xor(l_r, 32);
    const float inv = 1.0f / lsum;
    float* Or = O + (size_t)(q0w + cq) * D_;
    #pragma unroll
    for (int rq = 0; rq < 4; ++rq) {
        f32x4 w0, w1;
        #pragma unroll
        for (int i = 0; i < 4; ++i) {
            w0[i] = acc0[4 * rq + i] * inv;
            w1[i] = acc1[4 * rq + i] * inv;
        }
        *(f32x4*)(Or + 8 * rq + 4 * h)      = w0;
        *(f32x4*)(Or + 32 + 8 * rq + 4 * h) = w1;
    }
}

extern "C" void kernel_launch(void* const* d_in, const int* in_sizes, int n_in,
                              void* d_out, int out_size, void* d_ws, size_t ws_size,
                              hipStream_t stream) {
    const float* q = (const float*)d_in[0];
    const float* k = (const float*)d_in[1];
    const float* v = (const float*)d_in[2];
    float* out = (float*)d_out;
    dim3 grid(1024, 1, 1);
    dim3 block(128, 1, 1);
    fa_fwd<<<grid, block, 0, stream>>>(q, k, v, out);
}

// Round 7
// 54.451 us; speedup vs baseline: 1.5714x; 1.5714x over previous
//
#include <hip/hip_runtime.h>

#define S_ 2048
#define D_ 64

typedef __bf16 bf16x2v __attribute__((ext_vector_type(2)));
typedef __bf16 bf16x8 __attribute__((ext_vector_type(8)));
typedef float f32x2 __attribute__((ext_vector_type(2)));
typedef float f32x4 __attribute__((ext_vector_type(4)));
typedef float f32x16 __attribute__((ext_vector_type(16)));
typedef unsigned uint4v __attribute__((ext_vector_type(4)));

__device__ __forceinline__ unsigned cvtpk(float lo, float hi) {
    bf16x2v w; w[0] = (__bf16)lo; w[1] = (__bf16)hi;
    return __builtin_bit_cast(unsigned, w);  // fuses to v_cvt_pk_bf16_f32
}

// B-fragment (32x32x16, key-slice base b in packed-word space) from own/exchanged words
__device__ __forceinline__ bf16x8 mkfrag(const unsigned* u, const unsigned* ex, int b, int h) {
    uint4v w;
    w[0] = h ? ex[b + 2] : u[b];
    w[1] = h ? ex[b + 3] : u[b + 1];
    w[2] = h ? u[b + 2] : ex[b];
    w[3] = h ? u[b + 3] : ex[b + 1];
    return __builtin_bit_cast(bf16x8, w);
}

__global__ __launch_bounds__(256, 2)
void fa_fwd(const float* __restrict__ qg, const float* __restrict__ kg,
            const float* __restrict__ vg, float* __restrict__ og) {
    __shared__ __attribute__((aligned(16))) __bf16 K_lds[2][64 * 64];   // [key][d]
    __shared__ __attribute__((aligned(16))) __bf16 V_lds[2][64 * 64];   // [d][key]

    const int tid  = threadIdx.x;
    const int lane = tid & 63;
    const int wv   = tid >> 6;    // wave 0..3
    const int cq   = lane & 31;   // q-column this lane owns in all fragments
    const int h    = lane >> 5;   // half-wave index
    const int odd  = wv & 1;

    const int bid = blockIdx.x;  // 0..511
    // balanced pairing: CU slot k gets qt and 15-qt  (heavy first half)
    const int qt  = (bid < 256) ? (15 - (bid >> 5)) : ((bid >> 5) - 8);
    const int bh  = bid & 31;
    const int q0w = qt * 128 + wv * 32;  // this wave's 32 q-rows

    const size_t base = (size_t)bh * (S_ * D_);
    const float* Q = qg + base;
    const float* K = kg + base;
    const float* V = vg + base;
    float*       O = og + base;

    // ---- Q fragments (B-operand: lane holds Q[q0w+cq][c*16+8h+j]), scaled 1/8 ----
    bf16x8 qf[4];
    {
        const float* Qr = Q + (size_t)(q0w + cq) * D_;
        #pragma unroll
        for (int c = 0; c < 4; ++c) {
            const int d0 = c * 16 + h * 8;
            f32x4 a = *(const f32x4*)(Qr + d0);
            f32x4 b = *(const f32x4*)(Qr + d0 + 4);
            bf16x8 f;
            #pragma unroll
            for (int j = 0; j < 4; ++j) {
                f[j]     = (__bf16)(a[j] * 0.125f);
                f[4 + j] = (__bf16)(b[j] * 0.125f);
            }
            qf[c] = f;
        }
    }

    f32x16 acc0, acc1;  // O^T accumulators, d-blocks 0/1; lane's q = cq
    #pragma unroll
    for (int i = 0; i < 16; ++i) { acc0[i] = 0.f; acc1[i] = 0.f; }
    float m_r = -1e30f, l_r = 0.f;

    // staging maps (256 threads, one 64-key tile)
    const int kk  = tid >> 2;          // K row 0..63
    const int kd  = (tid & 3) * 16;    // K d-base (16 floats)
    const int vd2 = (tid & 31) * 2;    // V d-pair base
    const int vk8 = (tid >> 5) * 8;    // V key-base (8 keys)
    const int nt = 2 * qt + 2;
    const int tdiag = 2 * qt + (wv >> 1);
    const unsigned swq = (unsigned)((cq & 7) << 4);

    // ---- prologue loads (tile 0) ----
    f32x4 rk[4];
    f32x2 rv2[8];
    {
        const float* Kp = K + (size_t)kk * D_ + kd;
        #pragma unroll
        for (int i = 0; i < 4; ++i) rk[i] = *(const f32x4*)(Kp + 4 * i);
        const float* Vp = V + (size_t)vk8 * D_ + vd2;
        #pragma unroll
        for (int i = 0; i < 8; ++i) rv2[i] = *(const f32x2*)(Vp + (size_t)i * D_);
    }

    for (int t = 0; t < nt; ++t) {
        const int buf = t & 1;
        // ---- convert + LDS write of staged tile t ----
        {
            const unsigned swzk = (unsigned)((kk & 7) << 4);
            bf16x8 w0, w1;
            #pragma unroll
            for (int j = 0; j < 4; ++j) {
                w0[j]     = (__bf16)rk[0][j];
                w0[4 + j] = (__bf16)rk[1][j];
                w1[j]     = (__bf16)rk[2][j];
                w1[4 + j] = (__bf16)rk[3][j];
            }
            *(bf16x8*)(&K_lds[buf][kk * 64 + ((((unsigned)(2 * kd)) ^ swzk) >> 1)])      = w0;
            *(bf16x8*)(&K_lds[buf][kk * 64 + ((((unsigned)(2 * kd + 16)) ^ swzk) >> 1)]) = w1;
            #pragma unroll
            for (int j = 0; j < 2; ++j) {
                const int d = vd2 + j;
                bf16x8 wt;
                #pragma unroll
                for (int i = 0; i < 8; ++i) wt[i] = (__bf16)rv2[i][j];
                *(bf16x8*)(&V_lds[buf][d * 64 + ((((unsigned)(2 * vk8)) ^ ((unsigned)((d & 7) << 4))) >> 1)]) = wt;
            }
        }
        __syncthreads();

        // ---- prefetch tile t+1 (flies under compute) ----
        if (t + 1 < nt) {
            const int kv1 = (t + 1) * 64;
            const float* Kp = K + (size_t)(kv1 + kk) * D_ + kd;
            #pragma unroll
            for (int i = 0; i < 4; ++i) rk[i] = *(const f32x4*)(Kp + 4 * i);
            const float* Vp = V + (size_t)(kv1 + vk8) * D_ + vd2;
            #pragma unroll
            for (int i = 0; i < 8; ++i) rv2[i] = *(const f32x2*)(Vp + (size_t)i * D_);
        }

        if (t <= tdiag) {
            const bool diag  = (t == tdiag);
            const bool do_s1 = !diag || odd;   // even waves: s1 fully masked on diag
            const bool mask0 = diag && !odd;
            const bool mask1 = diag && odd;

            // ---- QK^T, swapped: S^T[key][q], q = cq lane-local ----
            f32x16 s0, s1;
            #pragma unroll
            for (int i = 0; i < 16; ++i) { s0[i] = 0.f; s1[i] = 0.f; }
            __builtin_amdgcn_s_setprio(1);
            #pragma unroll
            for (int c = 0; c < 4; ++c) {
                const unsigned co = (unsigned)(c * 32 + h * 16);
                bf16x8 a0 = *(const bf16x8*)(&K_lds[buf][cq * 64 + ((co ^ swq) >> 1)]);
                s0 = __builtin_amdgcn_mfma_f32_32x32x16_bf16(a0, qf[c], s0, 0, 0, 0);
            }
            if (do_s1) {
                #pragma unroll
                for (int c = 0; c < 4; ++c) {
                    const unsigned co = (unsigned)(c * 32 + h * 16);
                    bf16x8 a1 = *(const bf16x8*)(&K_lds[buf][(32 + cq) * 64 + ((co ^ swq) >> 1)]);
                    s1 = __builtin_amdgcn_mfma_f32_32x32x16_bf16(a1, qf[c], s1, 0, 0, 0);
                }
            }
            __builtin_amdgcn_s_setprio(0);

            // ---- causal mask: exactly one half needs idx>cq on the diag tile ----
            // C/D map: in-slice key idx = (reg&3) + 8*(reg>>2) + 4h  [m74/m101]
            if (mask0) {
                #pragma unroll
                for (int reg = 0; reg < 16; ++reg)
                    if (((reg & 3) + 8 * (reg >> 2) + 4 * h) > cq) s0[reg] = -1e30f;
            }
            if (mask1) {
                #pragma unroll
                for (int reg = 0; reg < 16; ++reg)
                    if (((reg & 3) + 8 * (reg >> 2) + 4 * h) > cq) s1[reg] = -1e30f;
            }

            // ---- row max: in-lane tree + one half-exchange shuffle ----
            float t8[8];
            #pragma unroll
            for (int i = 0; i < 8; ++i) {
                float a = fmaxf(s0[i], s0[i + 8]);
                if (do_s1) a = fmaxf(a, fmaxf(s1[i], s1[i + 8]));
                t8[i] = a;
            }
            float mx = fmaxf(fmaxf(fmaxf(t8[0], t8[4]), fmaxf(t8[1], t8[5])),
                             fmaxf(fmaxf(t8[2], t8[6]), fmaxf(t8[3], t8[7])));
            mx = fmaxf(mx, __shfl_xor(mx, 32));

            // ---- T13: defer rescale unless max grew past threshold ----
            if (!__all(mx <= m_r + 8.f)) {
                const float mnew = fmaxf(m_r, mx);
                const float corr = __expf(m_r - mnew);
                m_r = mnew;
                l_r *= corr;
                #pragma unroll
                for (int i = 0; i < 16; ++i) { acc0[i] *= corr; acc1[i] *= corr; }
            }

            // ---- exp (4-way partial-sum tree) ----
            float ps0 = 0.f, ps1 = 0.f, ps2 = 0.f, ps3 = 0.f;
            #pragma unroll
            for (int g = 0; g < 4; ++g) {
                s0[4 * g]     = __expf(s0[4 * g]     - m_r); ps0 += s0[4 * g];
                s0[4 * g + 1] = __expf(s0[4 * g + 1] - m_r); ps1 += s0[4 * g + 1];
                s0[4 * g + 2] = __expf(s0[4 * g + 2] - m_r); ps2 += s0[4 * g + 2];
                s0[4 * g + 3] = __expf(s0[4 * g + 3] - m_r); ps3 += s0[4 * g + 3];
            }
            if (do_s1) {
                #pragma unroll
                for (int g = 0; g < 4; ++g) {
                    s1[4 * g]     = __expf(s1[4 * g]     - m_r); ps0 += s1[4 * g];
                    s1[4 * g + 1] = __expf(s1[4 * g + 1] - m_r); ps1 += s1[4 * g + 1];
                    s1[4 * g + 2] = __expf(s1[4 * g + 2] - m_r); ps2 += s1[4 * g + 2];
                    s1[4 * g + 3] = __expf(s1[4 * g + 3] - m_r); ps3 += s1[4 * g + 3];
                }
            }
            l_r += (ps0 + ps1) + (ps2 + ps3);

            // ---- P -> packed bf16 words + half-exchange, all in-register ----
            // word u[2g+p] = keys (8g+4h+2p, +1) of lane's q-row
            unsigned u0[8], ex0[8], u1[8], ex1[8];
            #pragma unroll
            for (int g = 0; g < 4; ++g) {
                u0[2 * g]     = cvtpk(s0[4 * g],     s0[4 * g + 1]);
                u0[2 * g + 1] = cvtpk(s0[4 * g + 2], s0[4 * g + 3]);
            }
            #pragma unroll
            for (int i = 0; i < 8; ++i) ex0[i] = __shfl_xor(u0[i], 32);
            if (do_s1) {
                #pragma unroll
                for (int g = 0; g < 4; ++g) {
                    u1[2 * g]     = cvtpk(s1[4 * g],     s1[4 * g + 1]);
                    u1[2 * g + 1] = cvtpk(s1[4 * g + 2], s1[4 * g + 3]);
                }
                #pragma unroll
                for (int i = 0; i < 8; ++i) ex1[i] = __shfl_xor(u1[i], 32);
            }

            // ---- PV, swapped: O^T[d][q] += V^T · P^T ----
            __builtin_amdgcn_s_setprio(1);
            #pragma unroll
            for (int ks = 0; ks < 2; ++ks) {
                bf16x8 pb = mkfrag(u0, ex0, 4 * ks, h);
                const unsigned co = (unsigned)(ks * 32 + h * 16);
                bf16x8 va0 = *(const bf16x8*)(&V_lds[buf][cq * 64 + ((co ^ swq) >> 1)]);
                bf16x8 va1 = *(const bf16x8*)(&V_lds[buf][(32 + cq) * 64 + ((co ^ swq) >> 1)]);
                acc0 = __builtin_amdgcn_mfma_f32_32x32x16_bf16(va0, pb, acc0, 0, 0, 0);
                acc1 = __builtin_amdgcn_mfma_f32_32x32x16_bf16(va1, pb, acc1, 0, 0, 0);
            }
            if (do_s1) {
                #pragma unroll
                for (int ks = 0; ks < 2; ++ks) {
                    bf16x8 pb = mkfrag(u1, ex1, 4 * ks, h);
                    const unsigned co = (unsigned)((ks + 2) * 32 + h * 16);
                    bf16x8 va0 = *(const bf16x8*)(&V_lds[buf][cq * 64 + ((co ^ swq) >> 1)]);
                    bf16x8 va1 = *(const bf16x8*)(&V_lds[buf][(32 + cq) * 64 + ((co ^ swq) >> 1)]);
                    acc0 = __builtin_amdgcn_mfma_f32_32x32x16_bf16(va0, pb, acc0, 0, 0, 0);
                    acc1 = __builtin_amdgcn_mfma_f32_32x32x16_bf16(va1, pb, acc1, 0, 0, 0);
                }
            }
            __builtin_amdgcn_s_setprio(0);
        }
    }

    // ---- epilogue: combine l halves, normalize, store 16B chunks ----
    const float lsum = l_r + __shfl_xor(l_r, 32);
    const float inv = 1.0f / lsum;
    float* Or = O + (size_t)(q0w + cq) * D_;
    #pragma unroll
    for (int rq = 0; rq < 4; ++rq) {
        f32x4 w0, w1;
        #pragma unroll
        for (int i = 0; i < 4; ++i) {
            w0[i] = acc0[4 * rq + i] * inv;
            w1[i] = acc1[4 * rq + i] * inv;
        }
        *(f32x4*)(Or + 8 * rq + 4 * h)      = w0;
        *(f32x4*)(Or + 32 + 8 * rq + 4 * h) = w1;
    }
}

extern "C" void kernel_launch(void* const* d_in, const int* in_sizes, int n_in,
                              void* d_out, int out_size, void* d_ws, size_t ws_size,
                              hipStream_t stream) {
    const float* q = (const float*)d_in[0];
    const float* k = (const float*)d_in[1];
    const float* v = (const float*)d_in[2];
    float* out = (float*)d_out;
    dim3 grid(512, 1, 1);
    dim3 block(256, 1, 1);
    fa_fwd<<<grid, block, 0, stream>>>(q, k, v, out);
}